// Round 2
// baseline (297.742 us; speedup 1.0000x reference)
//
#include <hip/hip_runtime.h>

// Masked smooth-L1 sum over 2^25 fp32 pairs -> scalar. Memory/latency-bound.
// R2: maximize memory-level parallelism — each thread issues 8 independent
// 16B loads (4 float4 pairs) before any use; no loop; 8192 blocks.

__device__ __forceinline__ float sl1_masked(float o, float t) {
    float d = fabsf(o - t);
    float s = (d < 1.0f) ? (0.5f * d * d) : (d - 0.5f);
    return (t != 0.0f) ? s : 0.0f;
}

__global__ __launch_bounds__(256) void sl1_reduce_kernel(
    const float4* __restrict__ o4,
    const float4* __restrict__ t4,
    float* __restrict__ result,
    long long n4)
{
    // Each block covers 1024 consecutive float4 (16 KB per array).
    const long long base = (long long)blockIdx.x * 1024 + threadIdx.x;

    float4 o[4], t[4];
    if (base + 768 < n4) {
        // Fast path: issue all 8 loads back-to-back (independent, coalesced).
        #pragma unroll
        for (int k = 0; k < 4; ++k) {
            o[k] = o4[base + (long long)k * 256];
            t[k] = t4[base + (long long)k * 256];
        }
    } else {
        #pragma unroll
        for (int k = 0; k < 4; ++k) {
            long long idx = base + (long long)k * 256;
            if (idx < n4) { o[k] = o4[idx]; t[k] = t4[idx]; }
            else {
                o[k] = make_float4(0.f, 0.f, 0.f, 0.f);
                t[k] = make_float4(0.f, 0.f, 0.f, 0.f);
            }
        }
    }

    float acc = 0.0f;
    #pragma unroll
    for (int k = 0; k < 4; ++k) {
        acc += sl1_masked(o[k].x, t[k].x);
        acc += sl1_masked(o[k].y, t[k].y);
        acc += sl1_masked(o[k].z, t[k].z);
        acc += sl1_masked(o[k].w, t[k].w);
    }

    // wave-64 shuffle reduction
    #pragma unroll
    for (int off = 32; off > 0; off >>= 1)
        acc += __shfl_down(acc, off, 64);

    __shared__ float wave_sums[4];  // 256 threads = 4 waves
    const int lane = threadIdx.x & 63;
    const int wave = threadIdx.x >> 6;
    if (lane == 0) wave_sums[wave] = acc;
    __syncthreads();

    if (threadIdx.x == 0) {
        float s = wave_sums[0] + wave_sums[1] + wave_sums[2] + wave_sums[3];
        atomicAdd(result, s);  // one atomic per block (8192 total)
    }
}

extern "C" void kernel_launch(void* const* d_in, const int* in_sizes, int n_in,
                              void* d_out, int out_size, void* d_ws, size_t ws_size,
                              hipStream_t stream) {
    const float* out_p    = (const float*)d_in[0];
    const float* target_p = (const float*)d_in[1];
    float* res = (float*)d_out;

    const long long n  = (long long)in_sizes[0];  // 2^25
    const long long n4 = n / 4;                   // 8388608

    // d_out re-poisoned to 0xAA before every timed launch — zero it (capture-safe).
    hipMemsetAsync(res, 0, sizeof(float), stream);

    const int block = 256;
    const long long per_block = 1024;             // float4 per block
    const int grid = (int)((n4 + per_block - 1) / per_block);  // 8192
    sl1_reduce_kernel<<<grid, block, 0, stream>>>(
        (const float4*)out_p, (const float4*)target_p, res, n4);
}

// Round 3
// 254.552 us; speedup vs baseline: 1.1697x; 1.1697x over previous
//
#include <hip/hip_runtime.h>

// Masked smooth-L1 sum over 2^25 fp32 pairs -> scalar.
// R3: (1) nontemporal (no-allocate) loads — inputs exactly fill the 256 MiB
// L3 after the harness restore; regular streaming misses evict the
// not-yet-read resident lines (self-eviction cascade -> observed 50% miss).
// nt loads still look up L3 but don't allocate on miss.
// (2) per-block partials to d_ws + tiny second reducer (no same-address
// atomics, no memset dispatch). (3) 4096 blocks, 2-stage register pipeline.

typedef float v4f __attribute__((ext_vector_type(4)));

__device__ __forceinline__ float sl1_masked(float o, float t) {
    float d = fabsf(o - t);
    float s = (d < 1.0f) ? (0.5f * d * d) : (d - 0.5f);
    return (t != 0.0f) ? s : 0.0f;
}

__device__ __forceinline__ float sl1_v4(v4f o, v4f t) {
    return sl1_masked(o.x, t.x) + sl1_masked(o.y, t.y) +
           sl1_masked(o.z, t.z) + sl1_masked(o.w, t.w);
}

__device__ __forceinline__ float block_reduce(float acc) {
    #pragma unroll
    for (int off = 32; off > 0; off >>= 1)
        acc += __shfl_down(acc, off, 64);
    __shared__ float wave_sums[4];
    const int lane = threadIdx.x & 63;
    const int wave = threadIdx.x >> 6;
    if (lane == 0) wave_sums[wave] = acc;
    __syncthreads();
    return wave_sums[0] + wave_sums[1] + wave_sums[2] + wave_sums[3];
}

__global__ __launch_bounds__(256) void sl1_partial_kernel(
    const v4f* __restrict__ o4,
    const v4f* __restrict__ t4,
    float* __restrict__ partials,
    long long n4)
{
    const long long stride = (long long)gridDim.x * blockDim.x;
    long long i = (long long)blockIdx.x * blockDim.x + threadIdx.x;

    float acc = 0.0f;
    if (i < n4) {
        // 2-stage software pipeline: next pair in flight while computing cur.
        v4f o_cur = __builtin_nontemporal_load(&o4[i]);
        v4f t_cur = __builtin_nontemporal_load(&t4[i]);
        for (long long j = i + stride; j < n4; j += stride) {
            v4f o_nxt = __builtin_nontemporal_load(&o4[j]);
            v4f t_nxt = __builtin_nontemporal_load(&t4[j]);
            acc += sl1_v4(o_cur, t_cur);
            o_cur = o_nxt;
            t_cur = t_nxt;
        }
        acc += sl1_v4(o_cur, t_cur);
    }

    float s = block_reduce(acc);
    if (threadIdx.x == 0) partials[blockIdx.x] = s;
}

__global__ __launch_bounds__(256) void sl1_final_kernel(
    const float* __restrict__ partials,
    float* __restrict__ result,
    int n)
{
    float acc = 0.0f;
    for (int i = threadIdx.x; i < n; i += 256)
        acc += partials[i];
    float s = block_reduce(acc);
    if (threadIdx.x == 0) result[0] = s;  // plain store; d_out poison overwritten
}

extern "C" void kernel_launch(void* const* d_in, const int* in_sizes, int n_in,
                              void* d_out, int out_size, void* d_ws, size_t ws_size,
                              hipStream_t stream) {
    const v4f* o4 = (const v4f*)d_in[0];
    const v4f* t4 = (const v4f*)d_in[1];
    float* res      = (float*)d_out;
    float* partials = (float*)d_ws;

    const long long n  = (long long)in_sizes[0];  // 2^25
    const long long n4 = n / 4;                   // 8388608

    const int block = 256;
    const int grid  = 4096;  // 16384 waves = 64 waves/CU of work; 8 iters/thread

    sl1_partial_kernel<<<grid, block, 0, stream>>>(o4, t4, partials, n4);
    sl1_final_kernel<<<1, block, 0, stream>>>(partials, res, grid);
}

// Round 4
// 249.689 us; speedup vs baseline: 1.1924x; 1.0195x over previous
//
#include <hip/hip_runtime.h>

// Masked smooth-L1 sum over 2^25 fp32 pairs -> scalar.
// R4: block-contiguous chunks (64 KB/array/block -> sequential DRAM streams)
// + 4-deep register pipeline of nontemporal loads (8 loads in flight/thread,
// fully unrolled x16) + 2048 blocks (exactly-resident). Partials in d_ws,
// tiny final reducer (no atomics, no memset).

typedef float v4f __attribute__((ext_vector_type(4)));

#define ITERS 16                 // float4 pairs per thread
#define BLOCK 256
#define CHUNK (BLOCK * ITERS)    // 4096 float4 per block per array

__device__ __forceinline__ float sl1_masked(float o, float t) {
    float d = fabsf(o - t);
    float s = (d < 1.0f) ? (0.5f * d * d) : (d - 0.5f);
    return (t != 0.0f) ? s : 0.0f;
}

__device__ __forceinline__ float sl1_v4(v4f o, v4f t) {
    return sl1_masked(o.x, t.x) + sl1_masked(o.y, t.y) +
           sl1_masked(o.z, t.z) + sl1_masked(o.w, t.w);
}

__device__ __forceinline__ float block_reduce(float acc) {
    #pragma unroll
    for (int off = 32; off > 0; off >>= 1)
        acc += __shfl_down(acc, off, 64);
    __shared__ float wave_sums[BLOCK / 64];
    const int lane = threadIdx.x & 63;
    const int wave = threadIdx.x >> 6;
    if (lane == 0) wave_sums[wave] = acc;
    __syncthreads();
    return wave_sums[0] + wave_sums[1] + wave_sums[2] + wave_sums[3];
}

__global__ __launch_bounds__(BLOCK) void sl1_partial_kernel(
    const v4f* __restrict__ o4,
    const v4f* __restrict__ t4,
    float* __restrict__ partials,
    long long n4)
{
    const long long base = (long long)blockIdx.x * CHUNK + threadIdx.x;
    float acc = 0.0f;

    if (base + (ITERS - 1) * BLOCK < n4) {
        // Fast path: fully unrolled, 4-deep rotating pipeline.
        v4f o[4], t[4];
        #pragma unroll
        for (int k = 0; k < 4; ++k) {
            o[k] = __builtin_nontemporal_load(&o4[base + k * BLOCK]);
            t[k] = __builtin_nontemporal_load(&t4[base + k * BLOCK]);
        }
        #pragma unroll
        for (int k = 0; k < ITERS; ++k) {
            const int s = k & 3;
            acc += sl1_v4(o[s], t[s]);
            if (k + 4 < ITERS) {
                o[s] = __builtin_nontemporal_load(&o4[base + (k + 4) * BLOCK]);
                t[s] = __builtin_nontemporal_load(&t4[base + (k + 4) * BLOCK]);
            }
        }
    } else {
        #pragma unroll
        for (int k = 0; k < ITERS; ++k) {
            long long idx = base + (long long)k * BLOCK;
            if (idx < n4) {
                v4f o = __builtin_nontemporal_load(&o4[idx]);
                v4f t = __builtin_nontemporal_load(&t4[idx]);
                acc += sl1_v4(o, t);
            }
        }
    }

    float s = block_reduce(acc);
    if (threadIdx.x == 0) partials[blockIdx.x] = s;
}

__global__ __launch_bounds__(BLOCK) void sl1_final_kernel(
    const float* __restrict__ partials,
    float* __restrict__ result,
    int n)
{
    float acc = 0.0f;
    for (int i = threadIdx.x; i < n; i += BLOCK)
        acc += partials[i];
    float s = block_reduce(acc);
    if (threadIdx.x == 0) result[0] = s;
}

extern "C" void kernel_launch(void* const* d_in, const int* in_sizes, int n_in,
                              void* d_out, int out_size, void* d_ws, size_t ws_size,
                              hipStream_t stream) {
    const v4f* o4 = (const v4f*)d_in[0];
    const v4f* t4 = (const v4f*)d_in[1];
    float* res      = (float*)d_out;
    float* partials = (float*)d_ws;

    const long long n  = (long long)in_sizes[0];  // 2^25
    const long long n4 = n / 4;                   // 8388608 = 2048 * 4096

    const int grid = (int)((n4 + CHUNK - 1) / CHUNK);  // 2048
    sl1_partial_kernel<<<grid, BLOCK, 0, stream>>>(o4, t4, partials, n4);
    sl1_final_kernel<<<1, BLOCK, 0, stream>>>(partials, res, grid);
}